// Round 8
// baseline (340.178 us; speedup 1.0000x reference)
//
#include <hip/hip_runtime.h>
#include <hip/hip_fp16.h>

#define NF 128
#define NCHUNK 256          // counting-sort chunks (must equal k_redT/k_chunkbase block size)
#define NBMAX 1024          // max buckets => supports N <= 131072 (N=100000 here)

typedef _Float16 f16x8 __attribute__((ext_vector_type(8)));
typedef float    f32x4 __attribute__((ext_vector_type(4)));

// ---------------- Pass A: per-chunk bucket histogram (+ f32->f16 cvt blocks) ----------------
__global__ void k_histA(const int* __restrict__ dst, int* __restrict__ cnt, int n_edges, int epc,
                        const float* __restrict__ feat, __half* __restrict__ x0, int n8) {
    int bid = blockIdx.x;
    if (bid < NCHUNK) {
        __shared__ int h[NBMAX];
        for (int i = threadIdx.x; i < NBMAX; i += 256) h[i] = 0;
        __syncthreads();
        int e0 = bid * epc, e1 = min(e0 + epc, n_edges);
        for (int e = e0 + threadIdx.x; e < e1; e += 256)
            atomicAdd(&h[dst[e] >> 7], 1);
        __syncthreads();
        for (int i = threadIdx.x; i < NBMAX; i += 256)
            cnt[bid * NBMAX + i] = h[i];
    } else {
        int cb = bid - NCHUNK;
        const float4* f4 = reinterpret_cast<const float4*>(feat);
        for (int i8 = cb * 256 + threadIdx.x; i8 < n8; i8 += 512 * 256) {
            float4 v0 = f4[2 * i8];
            float4 v1 = f4[2 * i8 + 1];
            f16x8 o;
            o[0] = (_Float16)v0.x; o[1] = (_Float16)v0.y;
            o[2] = (_Float16)v0.z; o[3] = (_Float16)v0.w;
            o[4] = (_Float16)v1.x; o[5] = (_Float16)v1.y;
            o[6] = (_Float16)v1.z; o[7] = (_Float16)v1.w;
            reinterpret_cast<f16x8*>(x0)[i8] = o;
        }
    }
}

// ---------------- Pass B1: T[b] = sum_c cnt[c][b] ----------------
__global__ void k_redT(const int* __restrict__ cnt, int* __restrict__ T) {
    __shared__ int s[NCHUNK];
    int b = blockIdx.x;
    int tid = threadIdx.x;
    s[tid] = cnt[tid * NBMAX + b];
    __syncthreads();
    for (int o = NCHUNK / 2; o > 0; o >>= 1) {
        if (tid < o) s[tid] += s[tid + o];
        __syncthreads();
    }
    if (tid == 0) T[b] = s[0];
}

// ---------------- Pass B2: exclusive scan of T (single block, 1024 threads) ----------------
__global__ void k_scanT(const int* __restrict__ T, int* __restrict__ boff, int nb) {
    __shared__ int s[NBMAX];
    int tid = threadIdx.x;
    int v = (tid < nb) ? T[tid] : 0;
    s[tid] = v;
    __syncthreads();
    for (int o = 1; o < NBMAX; o <<= 1) {
        int t = (tid >= o) ? s[tid - o] : 0;
        __syncthreads();
        s[tid] += t;
        __syncthreads();
    }
    boff[tid] = s[tid] - v;
}

// ---------------- Pass B3: cnt[c][b] = boff[b] + prefix_{c'<c} cnt[c'][b] ----------------
__global__ void k_chunkbase(int* __restrict__ cnt, const int* __restrict__ boff) {
    __shared__ int s[NCHUNK];
    int b = blockIdx.x;
    int tid = threadIdx.x;
    int v = cnt[tid * NBMAX + b];
    s[tid] = v;
    __syncthreads();
    for (int o = 1; o < NCHUNK; o <<= 1) {
        int t = (tid >= o) ? s[tid - o] : 0;
        __syncthreads();
        s[tid] += t;
        __syncthreads();
    }
    cnt[tid * NBMAX + b] = boff[b] + s[tid] - v;
}

// ---------------- Pass C: scatter to bucket-grouped buffer, packed (dstLow<<17)|src ----------------
__global__ void k_scatC(const int* __restrict__ src, const int* __restrict__ dst,
                        const int* __restrict__ cnt, int* __restrict__ buf,
                        int n_edges, int epc) {
    __shared__ int base[NBMAX];
    __shared__ int h2[NBMAX];
    int c = blockIdx.x;
    for (int i = threadIdx.x; i < NBMAX; i += 256) {
        base[i] = cnt[c * NBMAX + i];
        h2[i] = 0;
    }
    __syncthreads();
    int e0 = c * epc, e1 = min(e0 + epc, n_edges);
    for (int e = e0 + threadIdx.x; e < e1; e += 256) {
        int d = dst[e];
        int b = d >> 7;
        int idx = atomicAdd(&h2[b], 1);            // LDS atomic: unique slot within (chunk,bucket)
        buf[base[b] + idx] = ((d & 127) << 17) | src[e];
    }
}

// ---------------- Pass D: per-bucket sort by low 7 bits -> csr, off, normv, invnv ----------------
__global__ void k_bucketD(const int* __restrict__ buf, const int* __restrict__ T,
                          const int* __restrict__ boff, int* __restrict__ csr,
                          int* __restrict__ off, float* __restrict__ normv,
                          float* __restrict__ invnv, int n_nodes, int n_edges, int nb) {
    __shared__ int h[128], pb[128], h2[128];
    int b = blockIdx.x;
    int tid = threadIdx.x;
    if (tid < 128) h[tid] = 0;
    __syncthreads();
    int bo = boff[b];
    int tb = T[b];
    for (int e = bo + tid; e < bo + tb; e += 256)
        atomicAdd(&h[(buf[e] >> 17) & 127], 1);
    __syncthreads();
    int v = (tid < 128) ? h[tid] : 0;
    if (tid < 128) pb[tid] = v;
    __syncthreads();
    for (int o = 1; o < 128; o <<= 1) {
        int t = (tid < 128 && tid >= o) ? pb[tid - o] : 0;
        __syncthreads();
        if (tid < 128) pb[tid] += t;
        __syncthreads();
    }
    if (tid < 128) {
        int ex = pb[tid] - v;                      // exclusive prefix within bucket
        pb[tid] = bo + ex;
        int node = b * 128 + tid;
        if (node < n_nodes) {
            off[node] = bo + ex;
            int d = (v < 1) ? 1 : v;
            normv[node] = rsqrtf((float)d);
            invnv[node] = sqrtf((float)d);
        }
        h2[tid] = 0;
    }
    __syncthreads();
    if (b == nb - 1 && tid == 0) off[n_nodes] = n_edges;
    for (int e = bo + tid; e < bo + tb; e += 256) {
        int p = buf[e];
        int dl = (p >> 17) & 127;
        int pos = pb[dl] + atomicAdd(&h2[dl], 1);
        csr[pos] = p & 0x1FFFF;
    }
}

// ---------------- unscaled gather core: accumulate one node's row (lane owns 16B chunk li) ----------------
__device__ __forceinline__ void gather_row_nosc(const __half* __restrict__ inp,  // in + li*8
                                                const int* __restrict__ csr,
                                                int e0, int e1, int g, float* fa /*[8]*/) {
    __half2 accA[4], accB[4];
#pragma unroll
    for (int j = 0; j < 4; ++j) {
        accA[j] = __half2half2(__float2half(0.f));
        accB[j] = __half2half2(__float2half(0.f));
    }
    int e = e0 + g;
    for (; e + 12 < e1; e += 16) {
        int sa = csr[e], sb = csr[e + 4], sc = csr[e + 8], sd = csr[e + 12];
        int4 ra = *reinterpret_cast<const int4*>(inp + (size_t)sa * NF);
        int4 rb = *reinterpret_cast<const int4*>(inp + (size_t)sb * NF);
        int4 rc = *reinterpret_cast<const int4*>(inp + (size_t)sc * NF);
        int4 rd = *reinterpret_cast<const int4*>(inp + (size_t)sd * NF);
        accA[0] = __hadd2(accA[0], __hadd2(__builtin_bit_cast(__half2, ra.x), __builtin_bit_cast(__half2, rc.x)));
        accA[1] = __hadd2(accA[1], __hadd2(__builtin_bit_cast(__half2, ra.y), __builtin_bit_cast(__half2, rc.y)));
        accA[2] = __hadd2(accA[2], __hadd2(__builtin_bit_cast(__half2, ra.z), __builtin_bit_cast(__half2, rc.z)));
        accA[3] = __hadd2(accA[3], __hadd2(__builtin_bit_cast(__half2, ra.w), __builtin_bit_cast(__half2, rc.w)));
        accB[0] = __hadd2(accB[0], __hadd2(__builtin_bit_cast(__half2, rb.x), __builtin_bit_cast(__half2, rd.x)));
        accB[1] = __hadd2(accB[1], __hadd2(__builtin_bit_cast(__half2, rb.y), __builtin_bit_cast(__half2, rd.y)));
        accB[2] = __hadd2(accB[2], __hadd2(__builtin_bit_cast(__half2, rb.z), __builtin_bit_cast(__half2, rd.z)));
        accB[3] = __hadd2(accB[3], __hadd2(__builtin_bit_cast(__half2, rb.w), __builtin_bit_cast(__half2, rd.w)));
    }
    for (; e + 4 < e1; e += 8) {
        int sa = csr[e], sb = csr[e + 4];
        int4 ra = *reinterpret_cast<const int4*>(inp + (size_t)sa * NF);
        int4 rb = *reinterpret_cast<const int4*>(inp + (size_t)sb * NF);
        accA[0] = __hadd2(accA[0], __builtin_bit_cast(__half2, ra.x));
        accA[1] = __hadd2(accA[1], __builtin_bit_cast(__half2, ra.y));
        accA[2] = __hadd2(accA[2], __builtin_bit_cast(__half2, ra.z));
        accA[3] = __hadd2(accA[3], __builtin_bit_cast(__half2, ra.w));
        accB[0] = __hadd2(accB[0], __builtin_bit_cast(__half2, rb.x));
        accB[1] = __hadd2(accB[1], __builtin_bit_cast(__half2, rb.y));
        accB[2] = __hadd2(accB[2], __builtin_bit_cast(__half2, rb.z));
        accB[3] = __hadd2(accB[3], __builtin_bit_cast(__half2, rb.w));
    }
    if (e < e1) {
        int sa = csr[e];
        int4 ra = *reinterpret_cast<const int4*>(inp + (size_t)sa * NF);
        accA[0] = __hadd2(accA[0], __builtin_bit_cast(__half2, ra.x));
        accA[1] = __hadd2(accA[1], __builtin_bit_cast(__half2, ra.y));
        accA[2] = __hadd2(accA[2], __builtin_bit_cast(__half2, ra.z));
        accA[3] = __hadd2(accA[3], __builtin_bit_cast(__half2, ra.w));
    }
#pragma unroll
    for (int j = 0; j < 4; ++j) {
        float2 f1 = __half22float2(accA[j]);
        float2 f2 = __half22float2(accB[j]);
        fa[2 * j] = f1.x + f2.x;
        fa[2 * j + 1] = f1.y + f2.y;
    }
}

// ---------------- gather: 1 wave/node, unroll-4 (16 rows in flight), dual half2 accumulators ----------------
// out[n] = normv[n]^2 * sum_e (EDGE_SCALE ? normv[src]*in[src] : in[src])
template<bool EDGE_SCALE>
__launch_bounds__(256)
__global__ void k_gather4(const __half* __restrict__ in, const int* __restrict__ csr,
                          const int* __restrict__ off, const float* __restrict__ normv,
                          __half* __restrict__ out, int n_nodes) {
    int wave = (blockIdx.x * blockDim.x + threadIdx.x) >> 6;
    int lane = threadIdx.x & 63;
    if (wave >= n_nodes) return;
    int e0 = off[wave], e1 = off[wave + 1];
    int g  = lane >> 4;    // edge slot 0..3
    int li = lane & 15;    // 16B chunk within row
    const __half* inp = in + li * 8;

    float fa[8];
    if (EDGE_SCALE) {
        __half2 accA[4], accB[4];
#pragma unroll
        for (int j = 0; j < 4; ++j) {
            accA[j] = __half2half2(__float2half(0.f));
            accB[j] = __half2half2(__float2half(0.f));
        }
        int e = e0 + g;
        for (; e + 12 < e1; e += 16) {
            int sa = csr[e], sb = csr[e + 4], sc = csr[e + 8], sd = csr[e + 12];
            int4 ra = *reinterpret_cast<const int4*>(inp + (size_t)sa * NF);
            int4 rb = *reinterpret_cast<const int4*>(inp + (size_t)sb * NF);
            int4 rc = *reinterpret_cast<const int4*>(inp + (size_t)sc * NF);
            int4 rd = *reinterpret_cast<const int4*>(inp + (size_t)sd * NF);
            __half2 fA = __float2half2_rn(normv[sa]);
            __half2 fB = __float2half2_rn(normv[sb]);
            __half2 fC = __float2half2_rn(normv[sc]);
            __half2 fD = __float2half2_rn(normv[sd]);
            accA[0] = __hfma2(__builtin_bit_cast(__half2, ra.x), fA, accA[0]);
            accA[1] = __hfma2(__builtin_bit_cast(__half2, ra.y), fA, accA[1]);
            accA[2] = __hfma2(__builtin_bit_cast(__half2, ra.z), fA, accA[2]);
            accA[3] = __hfma2(__builtin_bit_cast(__half2, ra.w), fA, accA[3]);
            accB[0] = __hfma2(__builtin_bit_cast(__half2, rb.x), fB, accB[0]);
            accB[1] = __hfma2(__builtin_bit_cast(__half2, rb.y), fB, accB[1]);
            accB[2] = __hfma2(__builtin_bit_cast(__half2, rb.z), fB, accB[2]);
            accB[3] = __hfma2(__builtin_bit_cast(__half2, rb.w), fB, accB[3]);
            accA[0] = __hfma2(__builtin_bit_cast(__half2, rc.x), fC, accA[0]);
            accA[1] = __hfma2(__builtin_bit_cast(__half2, rc.y), fC, accA[1]);
            accA[2] = __hfma2(__builtin_bit_cast(__half2, rc.z), fC, accA[2]);
            accA[3] = __hfma2(__builtin_bit_cast(__half2, rc.w), fC, accA[3]);
            accB[0] = __hfma2(__builtin_bit_cast(__half2, rd.x), fD, accB[0]);
            accB[1] = __hfma2(__builtin_bit_cast(__half2, rd.y), fD, accB[1]);
            accB[2] = __hfma2(__builtin_bit_cast(__half2, rd.z), fD, accB[2]);
            accB[3] = __hfma2(__builtin_bit_cast(__half2, rd.w), fD, accB[3]);
        }
        for (; e < e1; e += 4) {
            int sa = csr[e];
            int4 ra = *reinterpret_cast<const int4*>(inp + (size_t)sa * NF);
            __half2 fA = __float2half2_rn(normv[sa]);
            accA[0] = __hfma2(__builtin_bit_cast(__half2, ra.x), fA, accA[0]);
            accA[1] = __hfma2(__builtin_bit_cast(__half2, ra.y), fA, accA[1]);
            accA[2] = __hfma2(__builtin_bit_cast(__half2, ra.z), fA, accA[2]);
            accA[3] = __hfma2(__builtin_bit_cast(__half2, ra.w), fA, accA[3]);
        }
#pragma unroll
        for (int j = 0; j < 4; ++j) {
            float2 f1 = __half22float2(accA[j]);
            float2 f2 = __half22float2(accB[j]);
            fa[2 * j] = f1.x + f2.x;
            fa[2 * j + 1] = f1.y + f2.y;
        }
    } else {
        gather_row_nosc(inp, csr, e0, e1, g, fa);
    }

#pragma unroll
    for (int j = 0; j < 8; ++j) {
        fa[j] += __shfl_xor(fa[j], 16, 64);
        fa[j] += __shfl_xor(fa[j], 32, 64);
    }
    if (g == 0) {
        float nv = normv[wave];
        float nn2 = nv * nv;
        f16x8 o;
#pragma unroll
        for (int j = 0; j < 8; ++j) o[j] = (_Float16)(fa[j] * nn2);
        *reinterpret_cast<f16x8*>(out + (size_t)wave * NF + li * 8) = o;
    }
}

// ---------------- fused hop-3 gather + MFMA epilogue: 4 waves x 16 nodes per block ----------------
__launch_bounds__(256)
__global__ void k_gepi(const __half* __restrict__ x0, const __half* __restrict__ s1,
                       const __half* __restrict__ s2,
                       const int* __restrict__ csr, const int* __restrict__ off,
                       const float* __restrict__ normv, const float* __restrict__ invnv,
                       const float* __restrict__ fc_w, const float* __restrict__ fc_b,
                       const float* __restrict__ alpha, const float* __restrict__ head_w,
                       const float* __restrict__ head_b,
                       float* __restrict__ out_res, float* __restrict__ out_ent, int n_nodes) {
    __shared__ _Float16 fcw[128 * 136];
    __shared__ _Float16 srow[4][16][136];   // per-wave s3 rows (wave-local: no barrier needed)
    __shared__ float wlds[4][4][16];
    const int tid = threadIdx.x;
    const int lane = tid & 63;
    const int wid = tid >> 6;

    for (int i = 0; i < 16; ++i) {
        int idx = i * 1024 + tid * 4;
        int o = idx >> 7, f = idx & 127;
        float4 v = *reinterpret_cast<const float4*>(&fc_w[idx]);
        _Float16* p = &fcw[o * 136 + f];
        p[0] = (_Float16)v.x; p[1] = (_Float16)v.y;
        p[2] = (_Float16)v.z; p[3] = (_Float16)v.w;
    }
    __syncthreads();   // fcw ready; everything below is wave-local

    const int base = blockIdx.x * 64 + wid * 16;
    if (base + 16 > n_nodes) return;   // N % 16 == 0 here

    const int hi = lane >> 4;
    const int nx = lane & 15;
    const int g  = lane >> 4;          // gather edge slot
    const int li = lane & 15;          // gather 16B chunk

    // ---- phase 1: gather s3 rows for this wave's 16 nodes (from s2), store to LDS ----
    const __half* inp = s2 + li * 8;
    for (int j = 0; j < 16; ++j) {
        int n = base + j;
        float fa[8];
        gather_row_nosc(inp, csr, off[n], off[n + 1], g, fa);
#pragma unroll
        for (int q = 0; q < 8; ++q) {
            fa[q] += __shfl_xor(fa[q], 16, 64);
            fa[q] += __shfl_xor(fa[q], 32, 64);
        }
        if (g == 0) {
            float nv = normv[n];
            float nn2 = nv * nv;
            f16x8 o;
#pragma unroll
            for (int q = 0; q < 8; ++q) o[q] = (_Float16)(fa[q] * nn2);
            *reinterpret_cast<f16x8*>(&srow[wid][j][li * 8]) = o;
        }
    }

    // ---- phase 2: epilogue ----
    f16x8 bh[4];
#pragma unroll
    for (int kt = 0; kt < 4; ++kt) {
#pragma unroll
        for (int j = 0; j < 8; ++j)
            bh[kt][j] = (nx < 3) ? (_Float16)head_w[nx * NF + kt * 32 + hi * 8 + j] : (_Float16)0.f;
    }

    const __half* xs[3] = {x0, s1, s2};
    f16x8 a[4][4];
#pragma unroll
    for (int k = 0; k < 3; ++k) {
        const __half* xp = xs[k];
#pragma unroll
        for (int kt = 0; kt < 4; ++kt)
            a[k][kt] = *reinterpret_cast<const f16x8*>(xp + (size_t)(base + nx) * NF + kt * 32 + hi * 8);
    }
#pragma unroll
    for (int kt = 0; kt < 4; ++kt)
        a[3][kt] = *reinterpret_cast<const f16x8*>(&srow[wid][nx][kt * 32 + hi * 8]);

    f32x4 accL[4];
#pragma unroll
    for (int k = 0; k < 4; ++k) accL[k] = (f32x4){0.f, 0.f, 0.f, 0.f};
#pragma unroll
    for (int k = 0; k < 4; ++k)
#pragma unroll
        for (int kt = 0; kt < 4; ++kt)
            accL[k] = __builtin_amdgcn_mfma_f32_16x16x32_f16(a[k][kt], bh[kt], accL[k], 0, 0, 0);

    float4 in4 = *reinterpret_cast<const float4*>(&invnv[base + hi * 4]);
    float inr[4] = {in4.x, in4.y, in4.z, in4.w};
    float hb = (nx < 3) ? head_b[nx] : 0.f;
    float al0 = alpha[0], al1 = alpha[1], al2 = alpha[2], al3 = alpha[3];

#pragma unroll
    for (int r = 0; r < 4; ++r) {
        float ivx = inr[r];
        float l0 = accL[0][r] + hb;
        float l1 = fmaf(accL[1][r], ivx, hb);
        float l2 = fmaf(accL[2][r], ivx, hb);
        float l3 = fmaf(accL[3][r], ivx, hb);
        float mx = fmaxf(fmaxf(l0, l1), fmaxf(l2, l3));
        float e0 = __expf(l0 - mx), e1 = __expf(l1 - mx);
        float e2 = __expf(l2 - mx), e3 = __expf(l3 - mx);
        float s = e0 + e1 + e2 + e3;
        float inv = 1.f / s;
        float ls = __logf(s);
        float p0 = e0 * inv, p1 = e1 * inv, p2 = e2 * inv, p3 = e3 * inv;
        bool act = (nx < 3);
        float g0 = act ? p0 : 0.f, g1 = act ? p1 : 0.f;
        float g2 = act ? p2 : 0.f, g3 = act ? p3 : 0.f;
        float et = act ? -(p0 * (l0 - mx - ls) + p1 * (l1 - mx - ls) +
                           p2 * (l2 - mx - ls) + p3 * (l3 - mx - ls)) : 0.f;
        g0 += __shfl_xor(g0, 1, 64); g0 += __shfl_xor(g0, 2, 64);
        g1 += __shfl_xor(g1, 1, 64); g1 += __shfl_xor(g1, 2, 64);
        g2 += __shfl_xor(g2, 1, 64); g2 += __shfl_xor(g2, 2, 64);
        g3 += __shfl_xor(g3, 1, 64); g3 += __shfl_xor(g3, 2, 64);
        et += __shfl_xor(et, 1, 64); et += __shfl_xor(et, 2, 64);
        if (nx == 0) {
            int m = hi * 4 + r;
            wlds[wid][0][m] = al0 * g0;
            wlds[wid][1][m] = al1 * g1 * ivx;
            wlds[wid][2][m] = al2 * g2 * ivx;
            wlds[wid][3][m] = al3 * g3 * ivx;
            out_ent[base + m] = et;
        }
    }

    float ww0 = wlds[wid][0][nx];
    float ww1 = wlds[wid][1][nx];
    float ww2 = wlds[wid][2][nx];
    float ww3 = wlds[wid][3][nx];
    f16x8 ca[4];
#pragma unroll
    for (int kt = 0; kt < 4; ++kt) {
#pragma unroll
        for (int j = 0; j < 8; ++j) {
            float c = ww0 * (float)a[0][kt][j] + ww1 * (float)a[1][kt][j]
                    + ww2 * (float)a[2][kt][j] + ww3 * (float)a[3][kt][j];
            ca[kt][j] = (_Float16)c;
        }
    }

#pragma unroll
    for (int nt = 0; nt < 8; ++nt) {
        f32x4 acc = (f32x4){0.f, 0.f, 0.f, 0.f};
#pragma unroll
        for (int kt = 0; kt < 4; ++kt) {
            f16x8 b = *reinterpret_cast<const f16x8*>(&fcw[(nt * 16 + nx) * 136 + kt * 32 + hi * 8]);
            acc = __builtin_amdgcn_mfma_f32_16x16x32_f16(ca[kt], b, acc, 0, 0, 0);
        }
        float fcb4 = 4.f * fc_b[nt * 16 + nx];
#pragma unroll
        for (int r = 0; r < 4; ++r)
            out_res[(size_t)(base + hi * 4 + r) * NF + nt * 16 + nx] = acc[r] + fcb4;
    }
}

// ---------------- launch ----------------
extern "C" void kernel_launch(void* const* d_in, const int* in_sizes, int n_in,
                              void* d_out, int out_size, void* d_ws, size_t ws_size,
                              hipStream_t stream) {
    const float* feat   = (const float*)d_in[0];
    const float* fc_w   = (const float*)d_in[1];
    const float* fc_b   = (const float*)d_in[2];
    const float* alpha  = (const float*)d_in[3];
    const float* head_w = (const float*)d_in[4];
    const float* head_b = (const float*)d_in[5];
    const int*   src    = (const int*)d_in[6];
    const int*   dst    = (const int*)d_in[7];

    const int N = in_sizes[0] / NF;
    const int E = in_sizes[6];
    const int nb = (N + 127) / 128;       // buckets; N <= 131072

    char* ws = (char*)d_ws;
    size_t pos = 0;
    auto alloc = [&](size_t bytes) -> char* {
        char* p = ws + pos;
        pos = (pos + bytes + 255) & ~(size_t)255;
        return p;
    };
    int*    cnt   = (int*)   alloc((size_t)NCHUNK * NBMAX * 4);
    int*    T     = (int*)   alloc((size_t)NBMAX * 4);
    int*    boff  = (int*)   alloc((size_t)NBMAX * 4);
    int*    buf   = (int*)   alloc((size_t)E * 4);
    int*    csr   = (int*)   alloc((size_t)E * 4);
    int*    off   = (int*)   alloc((size_t)(N + 1) * 4);
    float*  normv = (float*) alloc((size_t)N * 4);
    float*  invnv = (float*) alloc((size_t)N * 4);
    __half* x0    = (__half*)alloc((size_t)N * NF * 2);
    __half* s1    = (__half*)alloc((size_t)N * NF * 2);
    __half* s2    = (__half*)alloc((size_t)N * NF * 2);
    if (pos > ws_size) return;

    float* out_res = (float*)d_out;
    float* out_ent = out_res + (size_t)N * NF;

    const int epc = (E + NCHUNK - 1) / NCHUNK;
    const int n8  = N * NF / 8;

    k_histA    <<<NCHUNK + 512, 256, 0, stream>>>(dst, cnt, E, epc, feat, x0, n8);
    k_redT     <<<nb, NCHUNK, 0, stream>>>(cnt, T);
    k_scanT    <<<1, NBMAX, 0, stream>>>(T, boff, nb);
    k_chunkbase<<<nb, NCHUNK, 0, stream>>>(cnt, boff);
    k_scatC    <<<NCHUNK, 256, 0, stream>>>(src, dst, cnt, buf, E, epc);
    k_bucketD  <<<nb, 256, 0, stream>>>(buf, T, boff, csr, off, normv, invnv, N, E, nb);

    const int gb = (N * 64 + 255) / 256;
    k_gather4<true> <<<gb, 256, 0, stream>>>(x0, csr, off, normv, s1, N);
    k_gather4<false><<<gb, 256, 0, stream>>>(s1, csr, off, normv, s2, N);

    const int eb = (N + 63) / 64;
    k_gepi<<<eb, 256, 0, stream>>>(x0, s1, s2, csr, off, normv, invnv, fc_w, fc_b,
                                   alpha, head_w, head_b, out_res, out_ent, N);
}

// Round 9
// 289.179 us; speedup vs baseline: 1.1764x; 1.1764x over previous
//
#include <hip/hip_runtime.h>
#include <hip/hip_fp16.h>

#define NF 128
#define NCHUNK 256          // counting-sort chunks (must equal k_redT/k_chunkbase block size)
#define NBMAX 1024          // max buckets => supports N <= 131072 (N=100000 here)

typedef _Float16 f16x8 __attribute__((ext_vector_type(8)));
typedef float    f32x4 __attribute__((ext_vector_type(4)));

// ---------------- Pass A: per-chunk bucket histogram (+ f32->f16 cvt blocks) ----------------
__global__ void k_histA(const int* __restrict__ dst, int* __restrict__ cnt, int n_edges, int epc,
                        const float* __restrict__ feat, __half* __restrict__ x0, int n8) {
    int bid = blockIdx.x;
    if (bid < NCHUNK) {
        __shared__ int h[NBMAX];
        for (int i = threadIdx.x; i < NBMAX; i += 256) h[i] = 0;
        __syncthreads();
        int e0 = bid * epc, e1 = min(e0 + epc, n_edges);
        for (int e = e0 + threadIdx.x; e < e1; e += 256)
            atomicAdd(&h[dst[e] >> 7], 1);
        __syncthreads();
        for (int i = threadIdx.x; i < NBMAX; i += 256)
            cnt[bid * NBMAX + i] = h[i];
    } else {
        int cb = bid - NCHUNK;
        const float4* f4 = reinterpret_cast<const float4*>(feat);
        for (int i8 = cb * 256 + threadIdx.x; i8 < n8; i8 += 512 * 256) {
            float4 v0 = f4[2 * i8];
            float4 v1 = f4[2 * i8 + 1];
            f16x8 o;
            o[0] = (_Float16)v0.x; o[1] = (_Float16)v0.y;
            o[2] = (_Float16)v0.z; o[3] = (_Float16)v0.w;
            o[4] = (_Float16)v1.x; o[5] = (_Float16)v1.y;
            o[6] = (_Float16)v1.z; o[7] = (_Float16)v1.w;
            __builtin_nontemporal_store(o, reinterpret_cast<f16x8*>(x0) + i8);
        }
    }
}

// ---------------- Pass B1: T[b] = sum_c cnt[c][b] ----------------
__global__ void k_redT(const int* __restrict__ cnt, int* __restrict__ T) {
    __shared__ int s[NCHUNK];
    int b = blockIdx.x;
    int tid = threadIdx.x;
    s[tid] = cnt[tid * NBMAX + b];
    __syncthreads();
    for (int o = NCHUNK / 2; o > 0; o >>= 1) {
        if (tid < o) s[tid] += s[tid + o];
        __syncthreads();
    }
    if (tid == 0) T[b] = s[0];
}

// ---------------- Pass B2: exclusive scan of T (single block, 1024 threads) ----------------
__global__ void k_scanT(const int* __restrict__ T, int* __restrict__ boff, int nb) {
    __shared__ int s[NBMAX];
    int tid = threadIdx.x;
    int v = (tid < nb) ? T[tid] : 0;
    s[tid] = v;
    __syncthreads();
    for (int o = 1; o < NBMAX; o <<= 1) {
        int t = (tid >= o) ? s[tid - o] : 0;
        __syncthreads();
        s[tid] += t;
        __syncthreads();
    }
    boff[tid] = s[tid] - v;
}

// ---------------- Pass B3: cnt[c][b] = boff[b] + prefix_{c'<c} cnt[c'][b] ----------------
__global__ void k_chunkbase(int* __restrict__ cnt, const int* __restrict__ boff) {
    __shared__ int s[NCHUNK];
    int b = blockIdx.x;
    int tid = threadIdx.x;
    int v = cnt[tid * NBMAX + b];
    s[tid] = v;
    __syncthreads();
    for (int o = 1; o < NCHUNK; o <<= 1) {
        int t = (tid >= o) ? s[tid - o] : 0;
        __syncthreads();
        s[tid] += t;
        __syncthreads();
    }
    cnt[tid * NBMAX + b] = boff[b] + s[tid] - v;
}

// ---------------- Pass C: scatter to bucket-grouped buffer, packed (dstLow<<17)|src ----------------
__global__ void k_scatC(const int* __restrict__ src, const int* __restrict__ dst,
                        const int* __restrict__ cnt, int* __restrict__ buf,
                        int n_edges, int epc) {
    __shared__ int base[NBMAX];
    __shared__ int h2[NBMAX];
    int c = blockIdx.x;
    for (int i = threadIdx.x; i < NBMAX; i += 256) {
        base[i] = cnt[c * NBMAX + i];
        h2[i] = 0;
    }
    __syncthreads();
    int e0 = c * epc, e1 = min(e0 + epc, n_edges);
    for (int e = e0 + threadIdx.x; e < e1; e += 256) {
        int d = dst[e];
        int b = d >> 7;
        int idx = atomicAdd(&h2[b], 1);            // LDS atomic: unique slot within (chunk,bucket)
        buf[base[b] + idx] = ((d & 127) << 17) | src[e];
    }
}

// ---------------- Pass D: per-bucket sort by low 7 bits -> csr, off, normv, invnv ----------------
__global__ void k_bucketD(const int* __restrict__ buf, const int* __restrict__ T,
                          const int* __restrict__ boff, int* __restrict__ csr,
                          int* __restrict__ off, float* __restrict__ normv,
                          float* __restrict__ invnv, int n_nodes, int n_edges, int nb) {
    __shared__ int h[128], pb[128], h2[128];
    int b = blockIdx.x;
    int tid = threadIdx.x;
    if (tid < 128) h[tid] = 0;
    __syncthreads();
    int bo = boff[b];
    int tb = T[b];
    for (int e = bo + tid; e < bo + tb; e += 256)
        atomicAdd(&h[(buf[e] >> 17) & 127], 1);
    __syncthreads();
    int v = (tid < 128) ? h[tid] : 0;
    if (tid < 128) pb[tid] = v;
    __syncthreads();
    for (int o = 1; o < 128; o <<= 1) {
        int t = (tid < 128 && tid >= o) ? pb[tid - o] : 0;
        __syncthreads();
        if (tid < 128) pb[tid] += t;
        __syncthreads();
    }
    if (tid < 128) {
        int ex = pb[tid] - v;                      // exclusive prefix within bucket
        pb[tid] = bo + ex;
        int node = b * 128 + tid;
        if (node < n_nodes) {
            off[node] = bo + ex;
            int d = (v < 1) ? 1 : v;
            normv[node] = rsqrtf((float)d);
            invnv[node] = sqrtf((float)d);
        }
        h2[tid] = 0;
    }
    __syncthreads();
    if (b == nb - 1 && tid == 0) off[n_nodes] = n_edges;
    for (int e = bo + tid; e < bo + tb; e += 256) {
        int p = buf[e];
        int dl = (p >> 17) & 127;
        int pos = pb[dl] + atomicAdd(&h2[dl], 1);
        csr[pos] = p & 0x1FFFF;
    }
}

// ---------------- gather: 1 wave/node, unroll-4 (16 rows in flight), dual half2 accumulators ----------------
// out[n] = normv[n]^2 * sum_e (EDGE_SCALE ? normv[src]*in[src] : in[src])
template<bool EDGE_SCALE>
__launch_bounds__(256)
__global__ void k_gather4(const __half* __restrict__ in, const int* __restrict__ csr,
                          const int* __restrict__ off, const float* __restrict__ normv,
                          __half* __restrict__ out, int n_nodes) {
    int wave = (blockIdx.x * blockDim.x + threadIdx.x) >> 6;
    int lane = threadIdx.x & 63;
    if (wave >= n_nodes) return;
    int e0 = off[wave], e1 = off[wave + 1];
    int g  = lane >> 4;    // edge slot 0..3
    int li = lane & 15;    // 16B chunk within row
    const __half* inp = in + li * 8;

    __half2 accA[4], accB[4];
#pragma unroll
    for (int j = 0; j < 4; ++j) {
        accA[j] = __half2half2(__float2half(0.f));
        accB[j] = __half2half2(__float2half(0.f));
    }
    int e = e0 + g;

    for (; e + 12 < e1; e += 16) {
        int sa = csr[e], sb = csr[e + 4], sc = csr[e + 8], sd = csr[e + 12];
        int4 ra = *reinterpret_cast<const int4*>(inp + (size_t)sa * NF);
        int4 rb = *reinterpret_cast<const int4*>(inp + (size_t)sb * NF);
        int4 rc = *reinterpret_cast<const int4*>(inp + (size_t)sc * NF);
        int4 rd = *reinterpret_cast<const int4*>(inp + (size_t)sd * NF);
        if (EDGE_SCALE) {
            __half2 fA = __float2half2_rn(normv[sa]);
            __half2 fB = __float2half2_rn(normv[sb]);
            __half2 fC = __float2half2_rn(normv[sc]);
            __half2 fD = __float2half2_rn(normv[sd]);
            accA[0] = __hfma2(__builtin_bit_cast(__half2, ra.x), fA, accA[0]);
            accA[1] = __hfma2(__builtin_bit_cast(__half2, ra.y), fA, accA[1]);
            accA[2] = __hfma2(__builtin_bit_cast(__half2, ra.z), fA, accA[2]);
            accA[3] = __hfma2(__builtin_bit_cast(__half2, ra.w), fA, accA[3]);
            accB[0] = __hfma2(__builtin_bit_cast(__half2, rb.x), fB, accB[0]);
            accB[1] = __hfma2(__builtin_bit_cast(__half2, rb.y), fB, accB[1]);
            accB[2] = __hfma2(__builtin_bit_cast(__half2, rb.z), fB, accB[2]);
            accB[3] = __hfma2(__builtin_bit_cast(__half2, rb.w), fB, accB[3]);
            accA[0] = __hfma2(__builtin_bit_cast(__half2, rc.x), fC, accA[0]);
            accA[1] = __hfma2(__builtin_bit_cast(__half2, rc.y), fC, accA[1]);
            accA[2] = __hfma2(__builtin_bit_cast(__half2, rc.z), fC, accA[2]);
            accA[3] = __hfma2(__builtin_bit_cast(__half2, rc.w), fC, accA[3]);
            accB[0] = __hfma2(__builtin_bit_cast(__half2, rd.x), fD, accB[0]);
            accB[1] = __hfma2(__builtin_bit_cast(__half2, rd.y), fD, accB[1]);
            accB[2] = __hfma2(__builtin_bit_cast(__half2, rd.z), fD, accB[2]);
            accB[3] = __hfma2(__builtin_bit_cast(__half2, rd.w), fD, accB[3]);
        } else {
            accA[0] = __hadd2(accA[0], __hadd2(__builtin_bit_cast(__half2, ra.x), __builtin_bit_cast(__half2, rc.x)));
            accA[1] = __hadd2(accA[1], __hadd2(__builtin_bit_cast(__half2, ra.y), __builtin_bit_cast(__half2, rc.y)));
            accA[2] = __hadd2(accA[2], __hadd2(__builtin_bit_cast(__half2, ra.z), __builtin_bit_cast(__half2, rc.z)));
            accA[3] = __hadd2(accA[3], __hadd2(__builtin_bit_cast(__half2, ra.w), __builtin_bit_cast(__half2, rc.w)));
            accB[0] = __hadd2(accB[0], __hadd2(__builtin_bit_cast(__half2, rb.x), __builtin_bit_cast(__half2, rd.x)));
            accB[1] = __hadd2(accB[1], __hadd2(__builtin_bit_cast(__half2, rb.y), __builtin_bit_cast(__half2, rd.y)));
            accB[2] = __hadd2(accB[2], __hadd2(__builtin_bit_cast(__half2, rb.z), __builtin_bit_cast(__half2, rd.z)));
            accB[3] = __hadd2(accB[3], __hadd2(__builtin_bit_cast(__half2, rb.w), __builtin_bit_cast(__half2, rd.w)));
        }
    }
    for (; e < e1; e += 4) {
        int sa = csr[e];
        int4 ra = *reinterpret_cast<const int4*>(inp + (size_t)sa * NF);
        if (EDGE_SCALE) {
            __half2 fA = __float2half2_rn(normv[sa]);
            accA[0] = __hfma2(__builtin_bit_cast(__half2, ra.x), fA, accA[0]);
            accA[1] = __hfma2(__builtin_bit_cast(__half2, ra.y), fA, accA[1]);
            accA[2] = __hfma2(__builtin_bit_cast(__half2, ra.z), fA, accA[2]);
            accA[3] = __hfma2(__builtin_bit_cast(__half2, ra.w), fA, accA[3]);
        } else {
            accA[0] = __hadd2(accA[0], __builtin_bit_cast(__half2, ra.x));
            accA[1] = __hadd2(accA[1], __builtin_bit_cast(__half2, ra.y));
            accA[2] = __hadd2(accA[2], __builtin_bit_cast(__half2, ra.z));
            accA[3] = __hadd2(accA[3], __builtin_bit_cast(__half2, ra.w));
        }
    }

    // merge dual accumulators + fold 4 edge-slot partials in f32
    float fa[8];
#pragma unroll
    for (int j = 0; j < 4; ++j) {
        float2 f1 = __half22float2(accA[j]);
        float2 f2 = __half22float2(accB[j]);
        fa[2 * j] = f1.x + f2.x;
        fa[2 * j + 1] = f1.y + f2.y;
    }
#pragma unroll
    for (int j = 0; j < 8; ++j) {
        fa[j] += __shfl_xor(fa[j], 16, 64);
        fa[j] += __shfl_xor(fa[j], 32, 64);
    }
    if (g == 0) {
        float nv = normv[wave];
        float nn2 = nv * nv;
        f16x8 o;
#pragma unroll
        for (int j = 0; j < 8; ++j) o[j] = (_Float16)(fa[j] * nn2);
        // non-temporal: output is never re-read by this kernel; keep L2 for gather rows
        __builtin_nontemporal_store(o, reinterpret_cast<f16x8*>(out + (size_t)wave * NF + li * 8));
    }
}

// ---------------- fused MFMA epilogue: 16 nodes per wave ----------------
__launch_bounds__(256)
__global__ void k_epi(const __half* __restrict__ x0, const __half* __restrict__ s1,
                      const __half* __restrict__ s2, const __half* __restrict__ s3,
                      const float* __restrict__ invnv,
                      const float* __restrict__ fc_w, const float* __restrict__ fc_b,
                      const float* __restrict__ alpha, const float* __restrict__ head_w,
                      const float* __restrict__ head_b,
                      float* __restrict__ out_res, float* __restrict__ out_ent, int n_nodes) {
    __shared__ _Float16 fcw[128 * 136];
    __shared__ float wlds[4][4][16];
    const int tid = threadIdx.x;
    const int lane = tid & 63;
    const int wid = tid >> 6;

    for (int i = 0; i < 16; ++i) {
        int idx = i * 1024 + tid * 4;
        int o = idx >> 7, f = idx & 127;
        float4 v = *reinterpret_cast<const float4*>(&fc_w[idx]);
        _Float16* p = &fcw[o * 136 + f];
        p[0] = (_Float16)v.x; p[1] = (_Float16)v.y;
        p[2] = (_Float16)v.z; p[3] = (_Float16)v.w;
    }
    __syncthreads();

    const int base = blockIdx.x * 64 + wid * 16;
    if (base + 16 > n_nodes) return;   // N % 16 == 0 here

    const int hi = lane >> 4;
    const int nx = lane & 15;

    f16x8 bh[4];
#pragma unroll
    for (int kt = 0; kt < 4; ++kt) {
#pragma unroll
        for (int j = 0; j < 8; ++j)
            bh[kt][j] = (nx < 3) ? (_Float16)head_w[nx * NF + kt * 32 + hi * 8 + j] : (_Float16)0.f;
    }

    const __half* xs[4] = {x0, s1, s2, s3};
    f16x8 a[4][4];
#pragma unroll
    for (int k = 0; k < 4; ++k) {
        const __half* xp = xs[k];
#pragma unroll
        for (int kt = 0; kt < 4; ++kt)
            a[k][kt] = *reinterpret_cast<const f16x8*>(xp + (size_t)(base + nx) * NF + kt * 32 + hi * 8);
    }

    f32x4 accL[4];
#pragma unroll
    for (int k = 0; k < 4; ++k) accL[k] = (f32x4){0.f, 0.f, 0.f, 0.f};
#pragma unroll
    for (int k = 0; k < 4; ++k)
#pragma unroll
        for (int kt = 0; kt < 4; ++kt)
            accL[k] = __builtin_amdgcn_mfma_f32_16x16x32_f16(a[k][kt], bh[kt], accL[k], 0, 0, 0);

    float4 in4 = *reinterpret_cast<const float4*>(&invnv[base + hi * 4]);
    float inr[4] = {in4.x, in4.y, in4.z, in4.w};
    float hb = (nx < 3) ? head_b[nx] : 0.f;
    float al0 = alpha[0], al1 = alpha[1], al2 = alpha[2], al3 = alpha[3];

#pragma unroll
    for (int r = 0; r < 4; ++r) {
        float ivx = inr[r];
        float l0 = accL[0][r] + hb;
        float l1 = fmaf(accL[1][r], ivx, hb);
        float l2 = fmaf(accL[2][r], ivx, hb);
        float l3 = fmaf(accL[3][r], ivx, hb);
        float mx = fmaxf(fmaxf(l0, l1), fmaxf(l2, l3));
        float e0 = __expf(l0 - mx), e1 = __expf(l1 - mx);
        float e2 = __expf(l2 - mx), e3 = __expf(l3 - mx);
        float s = e0 + e1 + e2 + e3;
        float inv = 1.f / s;
        float ls = __logf(s);
        float p0 = e0 * inv, p1 = e1 * inv, p2 = e2 * inv, p3 = e3 * inv;
        bool act = (nx < 3);
        float g0 = act ? p0 : 0.f, g1 = act ? p1 : 0.f;
        float g2 = act ? p2 : 0.f, g3 = act ? p3 : 0.f;
        float et = act ? -(p0 * (l0 - mx - ls) + p1 * (l1 - mx - ls) +
                           p2 * (l2 - mx - ls) + p3 * (l3 - mx - ls)) : 0.f;
        g0 += __shfl_xor(g0, 1, 64); g0 += __shfl_xor(g0, 2, 64);
        g1 += __shfl_xor(g1, 1, 64); g1 += __shfl_xor(g1, 2, 64);
        g2 += __shfl_xor(g2, 1, 64); g2 += __shfl_xor(g2, 2, 64);
        g3 += __shfl_xor(g3, 1, 64); g3 += __shfl_xor(g3, 2, 64);
        et += __shfl_xor(et, 1, 64); et += __shfl_xor(et, 2, 64);
        if (nx == 0) {
            int m = hi * 4 + r;
            wlds[wid][0][m] = al0 * g0;
            wlds[wid][1][m] = al1 * g1 * ivx;
            wlds[wid][2][m] = al2 * g2 * ivx;
            wlds[wid][3][m] = al3 * g3 * ivx;
            out_ent[base + m] = et;
        }
    }

    float ww0 = wlds[wid][0][nx];
    float ww1 = wlds[wid][1][nx];
    float ww2 = wlds[wid][2][nx];
    float ww3 = wlds[wid][3][nx];
    f16x8 ca[4];
#pragma unroll
    for (int kt = 0; kt < 4; ++kt) {
#pragma unroll
        for (int j = 0; j < 8; ++j) {
            float c = ww0 * (float)a[0][kt][j] + ww1 * (float)a[1][kt][j]
                    + ww2 * (float)a[2][kt][j] + ww3 * (float)a[3][kt][j];
            ca[kt][j] = (_Float16)c;
        }
    }

#pragma unroll
    for (int nt = 0; nt < 8; ++nt) {
        f32x4 acc = (f32x4){0.f, 0.f, 0.f, 0.f};
#pragma unroll
        for (int kt = 0; kt < 4; ++kt) {
            f16x8 b = *reinterpret_cast<const f16x8*>(&fcw[(nt * 16 + nx) * 136 + kt * 32 + hi * 8]);
            acc = __builtin_amdgcn_mfma_f32_16x16x32_f16(ca[kt], b, acc, 0, 0, 0);
        }
        float fcb4 = 4.f * fc_b[nt * 16 + nx];
#pragma unroll
        for (int r = 0; r < 4; ++r)
            __builtin_nontemporal_store(acc[r] + fcb4,
                &out_res[(size_t)(base + hi * 4 + r) * NF + nt * 16 + nx]);
    }
}

// ---------------- launch ----------------
extern "C" void kernel_launch(void* const* d_in, const int* in_sizes, int n_in,
                              void* d_out, int out_size, void* d_ws, size_t ws_size,
                              hipStream_t stream) {
    const float* feat   = (const float*)d_in[0];
    const float* fc_w   = (const float*)d_in[1];
    const float* fc_b   = (const float*)d_in[2];
    const float* alpha  = (const float*)d_in[3];
    const float* head_w = (const float*)d_in[4];
    const float* head_b = (const float*)d_in[5];
    const int*   src    = (const int*)d_in[6];
    const int*   dst    = (const int*)d_in[7];

    const int N = in_sizes[0] / NF;
    const int E = in_sizes[6];
    const int nb = (N + 127) / 128;       // buckets; N <= 131072

    char* ws = (char*)d_ws;
    size_t pos = 0;
    auto alloc = [&](size_t bytes) -> char* {
        char* p = ws + pos;
        pos = (pos + bytes + 255) & ~(size_t)255;
        return p;
    };
    int*    cnt   = (int*)   alloc((size_t)NCHUNK * NBMAX * 4);
    int*    T     = (int*)   alloc((size_t)NBMAX * 4);
    int*    boff  = (int*)   alloc((size_t)NBMAX * 4);
    int*    buf   = (int*)   alloc((size_t)E * 4);
    int*    csr   = (int*)   alloc((size_t)E * 4);
    int*    off   = (int*)   alloc((size_t)(N + 1) * 4);
    float*  normv = (float*) alloc((size_t)N * 4);
    float*  invnv = (float*) alloc((size_t)N * 4);
    __half* x0    = (__half*)alloc((size_t)N * NF * 2);
    __half* s1    = (__half*)alloc((size_t)N * NF * 2);
    __half* s2    = (__half*)alloc((size_t)N * NF * 2);
    __half* s3    = (__half*)alloc((size_t)N * NF * 2);
    if (pos > ws_size) return;

    float* out_res = (float*)d_out;
    float* out_ent = out_res + (size_t)N * NF;

    const int epc = (E + NCHUNK - 1) / NCHUNK;
    const int n8  = N * NF / 8;

    k_histA    <<<NCHUNK + 512, 256, 0, stream>>>(dst, cnt, E, epc, feat, x0, n8);
    k_redT     <<<nb, NCHUNK, 0, stream>>>(cnt, T);
    k_scanT    <<<1, NBMAX, 0, stream>>>(T, boff, nb);
    k_chunkbase<<<nb, NCHUNK, 0, stream>>>(cnt, boff);
    k_scatC    <<<NCHUNK, 256, 0, stream>>>(src, dst, cnt, buf, E, epc);
    k_bucketD  <<<nb, 256, 0, stream>>>(buf, T, boff, csr, off, normv, invnv, N, E, nb);

    const int gb = (N * 64 + 255) / 256;
    k_gather4<true> <<<gb, 256, 0, stream>>>(x0, csr, off, normv, s1, N);
    k_gather4<false><<<gb, 256, 0, stream>>>(s1, csr, off, normv, s2, N);
    k_gather4<false><<<gb, 256, 0, stream>>>(s2, csr, off, normv, s3, N);

    const int eb = (N + 63) / 64;
    k_epi<<<eb, 256, 0, stream>>>(x0, s1, s2, s3, invnv, fc_w, fc_b,
                                  alpha, head_w, head_b, out_res, out_ent, N);
}

// Round 10
// 280.550 us; speedup vs baseline: 1.2125x; 1.0308x over previous
//
#include <hip/hip_runtime.h>
#include <hip/hip_fp16.h>

#define NF 128
#define NCHUNK 256          // counting-sort chunks (must equal k_redT/k_chunkbase block size)
#define NBMAX 1024          // max buckets => supports N <= 131072 (N=100000 here)

typedef _Float16 f16x8 __attribute__((ext_vector_type(8)));
typedef float    f32x4 __attribute__((ext_vector_type(4)));

// ---------------- Pass A: per-chunk bucket histogram (+ f32->f16 cvt blocks) ----------------
__global__ void k_histA(const int* __restrict__ dst, int* __restrict__ cnt, int n_edges, int epc,
                        const float* __restrict__ feat, __half* __restrict__ x0, int n8) {
    int bid = blockIdx.x;
    if (bid < NCHUNK) {
        __shared__ int h[NBMAX];
        for (int i = threadIdx.x; i < NBMAX; i += 256) h[i] = 0;
        __syncthreads();
        int e0 = bid * epc, e1 = min(e0 + epc, n_edges);
        for (int e = e0 + threadIdx.x; e < e1; e += 256)
            atomicAdd(&h[dst[e] >> 7], 1);
        __syncthreads();
        for (int i = threadIdx.x; i < NBMAX; i += 256)
            cnt[bid * NBMAX + i] = h[i];
    } else {
        int cb = bid - NCHUNK;
        const float4* f4 = reinterpret_cast<const float4*>(feat);
        for (int i8 = cb * 256 + threadIdx.x; i8 < n8; i8 += 512 * 256) {
            float4 v0 = f4[2 * i8];
            float4 v1 = f4[2 * i8 + 1];
            f16x8 o;
            o[0] = (_Float16)v0.x; o[1] = (_Float16)v0.y;
            o[2] = (_Float16)v0.z; o[3] = (_Float16)v0.w;
            o[4] = (_Float16)v1.x; o[5] = (_Float16)v1.y;
            o[6] = (_Float16)v1.z; o[7] = (_Float16)v1.w;
            reinterpret_cast<f16x8*>(x0)[i8] = o;
        }
    }
}

// ---------------- Pass B1: T[b] = sum_c cnt[c][b] ----------------
__global__ void k_redT(const int* __restrict__ cnt, int* __restrict__ T) {
    __shared__ int s[NCHUNK];
    int b = blockIdx.x;
    int tid = threadIdx.x;
    s[tid] = cnt[tid * NBMAX + b];
    __syncthreads();
    for (int o = NCHUNK / 2; o > 0; o >>= 1) {
        if (tid < o) s[tid] += s[tid + o];
        __syncthreads();
    }
    if (tid == 0) T[b] = s[0];
}

// ---------------- Pass B2: exclusive scan of T (single block, 1024 threads) ----------------
__global__ void k_scanT(const int* __restrict__ T, int* __restrict__ boff, int nb) {
    __shared__ int s[NBMAX];
    int tid = threadIdx.x;
    int v = (tid < nb) ? T[tid] : 0;
    s[tid] = v;
    __syncthreads();
    for (int o = 1; o < NBMAX; o <<= 1) {
        int t = (tid >= o) ? s[tid - o] : 0;
        __syncthreads();
        s[tid] += t;
        __syncthreads();
    }
    boff[tid] = s[tid] - v;
}

// ---------------- Pass B3: cnt[c][b] = boff[b] + prefix_{c'<c} cnt[c'][b] ----------------
__global__ void k_chunkbase(int* __restrict__ cnt, const int* __restrict__ boff) {
    __shared__ int s[NCHUNK];
    int b = blockIdx.x;
    int tid = threadIdx.x;
    int v = cnt[tid * NBMAX + b];
    s[tid] = v;
    __syncthreads();
    for (int o = 1; o < NCHUNK; o <<= 1) {
        int t = (tid >= o) ? s[tid - o] : 0;
        __syncthreads();
        s[tid] += t;
        __syncthreads();
    }
    cnt[tid * NBMAX + b] = boff[b] + s[tid] - v;
}

// ---------------- Pass C: scatter to bucket-grouped buffer, packed (dstLow<<17)|src ----------------
__global__ void k_scatC(const int* __restrict__ src, const int* __restrict__ dst,
                        const int* __restrict__ cnt, int* __restrict__ buf,
                        int n_edges, int epc) {
    __shared__ int base[NBMAX];
    __shared__ int h2[NBMAX];
    int c = blockIdx.x;
    for (int i = threadIdx.x; i < NBMAX; i += 256) {
        base[i] = cnt[c * NBMAX + i];
        h2[i] = 0;
    }
    __syncthreads();
    int e0 = c * epc, e1 = min(e0 + epc, n_edges);
    for (int e = e0 + threadIdx.x; e < e1; e += 256) {
        int d = dst[e];
        int b = d >> 7;
        int idx = atomicAdd(&h2[b], 1);            // LDS atomic: unique slot within (chunk,bucket)
        buf[base[b] + idx] = ((d & 127) << 17) | src[e];
    }
}

// ---------------- Pass D: per-bucket sort by low 7 bits -> csr, off, normv, normh, invnv ----------------
__global__ void k_bucketD(const int* __restrict__ buf, const int* __restrict__ T,
                          const int* __restrict__ boff, int* __restrict__ csr,
                          int* __restrict__ off, float* __restrict__ normv,
                          __half* __restrict__ normh,
                          float* __restrict__ invnv, int n_nodes, int n_edges, int nb) {
    __shared__ int h[128], pb[128], h2[128];
    int b = blockIdx.x;
    int tid = threadIdx.x;
    if (tid < 128) h[tid] = 0;
    __syncthreads();
    int bo = boff[b];
    int tb = T[b];
    for (int e = bo + tid; e < bo + tb; e += 256)
        atomicAdd(&h[(buf[e] >> 17) & 127], 1);
    __syncthreads();
    int v = (tid < 128) ? h[tid] : 0;
    if (tid < 128) pb[tid] = v;
    __syncthreads();
    for (int o = 1; o < 128; o <<= 1) {
        int t = (tid < 128 && tid >= o) ? pb[tid - o] : 0;
        __syncthreads();
        if (tid < 128) pb[tid] += t;
        __syncthreads();
    }
    if (tid < 128) {
        int ex = pb[tid] - v;                      // exclusive prefix within bucket
        pb[tid] = bo + ex;
        int node = b * 128 + tid;
        if (node < n_nodes) {
            off[node] = bo + ex;
            int d = (v < 1) ? 1 : v;
            float nv = rsqrtf((float)d);
            normv[node] = nv;
            normh[node] = __float2half(nv);        // same rounding gather-1 applied per edge
            invnv[node] = sqrtf((float)d);
        }
        h2[tid] = 0;
    }
    __syncthreads();
    if (b == nb - 1 && tid == 0) off[n_nodes] = n_edges;
    for (int e = bo + tid; e < bo + tb; e += 256) {
        int p = buf[e];
        int dl = (p >> 17) & 127;
        int pos = pb[dl] + atomicAdd(&h2[dl], 1);
        csr[pos] = p & 0x1FFFF;
    }
}

// ---------------- gather: 1 wave/node, unroll-4 (16 rows in flight), dual half2 accumulators ----------------
// out[n] = normv[n]^2 * sum_e (EDGE_SCALE ? normh[src]*in[src] : in[src])
template<bool EDGE_SCALE>
__launch_bounds__(256)
__global__ void k_gather4(const __half* __restrict__ in, const int* __restrict__ csr,
                          const int* __restrict__ off, const float* __restrict__ normv,
                          const __half* __restrict__ normh,
                          __half* __restrict__ out, int n_nodes) {
    int wave = (blockIdx.x * blockDim.x + threadIdx.x) >> 6;
    int lane = threadIdx.x & 63;
    if (wave >= n_nodes) return;
    int e0 = off[wave], e1 = off[wave + 1];
    int g  = lane >> 4;    // edge slot 0..3
    int li = lane & 15;    // 16B chunk within row
    const __half* inp = in + li * 8;

    __half2 accA[4], accB[4];
#pragma unroll
    for (int j = 0; j < 4; ++j) {
        accA[j] = __half2half2(__float2half(0.f));
        accB[j] = __half2half2(__float2half(0.f));
    }
    int e = e0 + g;

    for (; e + 12 < e1; e += 16) {
        int sa = csr[e], sb = csr[e + 4], sc = csr[e + 8], sd = csr[e + 12];
        int4 ra = *reinterpret_cast<const int4*>(inp + (size_t)sa * NF);
        int4 rb = *reinterpret_cast<const int4*>(inp + (size_t)sb * NF);
        int4 rc = *reinterpret_cast<const int4*>(inp + (size_t)sc * NF);
        int4 rd = *reinterpret_cast<const int4*>(inp + (size_t)sd * NF);
        if (EDGE_SCALE) {
            __half2 fA = __half2half2(normh[sa]);
            __half2 fB = __half2half2(normh[sb]);
            __half2 fC = __half2half2(normh[sc]);
            __half2 fD = __half2half2(normh[sd]);
            accA[0] = __hfma2(__builtin_bit_cast(__half2, ra.x), fA, accA[0]);
            accA[1] = __hfma2(__builtin_bit_cast(__half2, ra.y), fA, accA[1]);
            accA[2] = __hfma2(__builtin_bit_cast(__half2, ra.z), fA, accA[2]);
            accA[3] = __hfma2(__builtin_bit_cast(__half2, ra.w), fA, accA[3]);
            accB[0] = __hfma2(__builtin_bit_cast(__half2, rb.x), fB, accB[0]);
            accB[1] = __hfma2(__builtin_bit_cast(__half2, rb.y), fB, accB[1]);
            accB[2] = __hfma2(__builtin_bit_cast(__half2, rb.z), fB, accB[2]);
            accB[3] = __hfma2(__builtin_bit_cast(__half2, rb.w), fB, accB[3]);
            accA[0] = __hfma2(__builtin_bit_cast(__half2, rc.x), fC, accA[0]);
            accA[1] = __hfma2(__builtin_bit_cast(__half2, rc.y), fC, accA[1]);
            accA[2] = __hfma2(__builtin_bit_cast(__half2, rc.z), fC, accA[2]);
            accA[3] = __hfma2(__builtin_bit_cast(__half2, rc.w), fC, accA[3]);
            accB[0] = __hfma2(__builtin_bit_cast(__half2, rd.x), fD, accB[0]);
            accB[1] = __hfma2(__builtin_bit_cast(__half2, rd.y), fD, accB[1]);
            accB[2] = __hfma2(__builtin_bit_cast(__half2, rd.z), fD, accB[2]);
            accB[3] = __hfma2(__builtin_bit_cast(__half2, rd.w), fD, accB[3]);
        } else {
            accA[0] = __hadd2(accA[0], __hadd2(__builtin_bit_cast(__half2, ra.x), __builtin_bit_cast(__half2, rc.x)));
            accA[1] = __hadd2(accA[1], __hadd2(__builtin_bit_cast(__half2, ra.y), __builtin_bit_cast(__half2, rc.y)));
            accA[2] = __hadd2(accA[2], __hadd2(__builtin_bit_cast(__half2, ra.z), __builtin_bit_cast(__half2, rc.z)));
            accA[3] = __hadd2(accA[3], __hadd2(__builtin_bit_cast(__half2, ra.w), __builtin_bit_cast(__half2, rc.w)));
            accB[0] = __hadd2(accB[0], __hadd2(__builtin_bit_cast(__half2, rb.x), __builtin_bit_cast(__half2, rd.x)));
            accB[1] = __hadd2(accB[1], __hadd2(__builtin_bit_cast(__half2, rb.y), __builtin_bit_cast(__half2, rd.y)));
            accB[2] = __hadd2(accB[2], __hadd2(__builtin_bit_cast(__half2, rb.z), __builtin_bit_cast(__half2, rd.z)));
            accB[3] = __hadd2(accB[3], __hadd2(__builtin_bit_cast(__half2, rb.w), __builtin_bit_cast(__half2, rd.w)));
        }
    }
    for (; e < e1; e += 4) {
        int sa = csr[e];
        int4 ra = *reinterpret_cast<const int4*>(inp + (size_t)sa * NF);
        if (EDGE_SCALE) {
            __half2 fA = __half2half2(normh[sa]);
            accA[0] = __hfma2(__builtin_bit_cast(__half2, ra.x), fA, accA[0]);
            accA[1] = __hfma2(__builtin_bit_cast(__half2, ra.y), fA, accA[1]);
            accA[2] = __hfma2(__builtin_bit_cast(__half2, ra.z), fA, accA[2]);
            accA[3] = __hfma2(__builtin_bit_cast(__half2, ra.w), fA, accA[3]);
        } else {
            accA[0] = __hadd2(accA[0], __builtin_bit_cast(__half2, ra.x));
            accA[1] = __hadd2(accA[1], __builtin_bit_cast(__half2, ra.y));
            accA[2] = __hadd2(accA[2], __builtin_bit_cast(__half2, ra.z));
            accA[3] = __hadd2(accA[3], __builtin_bit_cast(__half2, ra.w));
        }
    }

    // merge dual accumulators + fold 4 edge-slot partials in f32
    float fa[8];
#pragma unroll
    for (int j = 0; j < 4; ++j) {
        float2 f1 = __half22float2(accA[j]);
        float2 f2 = __half22float2(accB[j]);
        fa[2 * j] = f1.x + f2.x;
        fa[2 * j + 1] = f1.y + f2.y;
    }
#pragma unroll
    for (int j = 0; j < 8; ++j) {
        fa[j] += __shfl_xor(fa[j], 16, 64);
        fa[j] += __shfl_xor(fa[j], 32, 64);
    }
    if (g == 0) {
        float nv = normv[wave];
        float nn2 = nv * nv;
        f16x8 o;
#pragma unroll
        for (int j = 0; j < 8; ++j) o[j] = (_Float16)(fa[j] * nn2);
        *reinterpret_cast<f16x8*>(out + (size_t)wave * NF + li * 8) = o;
    }
}

// ---------------- fused MFMA epilogue: 16 nodes per wave ----------------
__launch_bounds__(256)
__global__ void k_epi(const __half* __restrict__ x0, const __half* __restrict__ s1,
                      const __half* __restrict__ s2, const __half* __restrict__ s3,
                      const float* __restrict__ invnv,
                      const float* __restrict__ fc_w, const float* __restrict__ fc_b,
                      const float* __restrict__ alpha, const float* __restrict__ head_w,
                      const float* __restrict__ head_b,
                      float* __restrict__ out_res, float* __restrict__ out_ent, int n_nodes) {
    __shared__ _Float16 fcw[128 * 136];
    __shared__ float wlds[4][4][16];
    const int tid = threadIdx.x;
    const int lane = tid & 63;
    const int wid = tid >> 6;

    for (int i = 0; i < 16; ++i) {
        int idx = i * 1024 + tid * 4;
        int o = idx >> 7, f = idx & 127;
        float4 v = *reinterpret_cast<const float4*>(&fc_w[idx]);
        _Float16* p = &fcw[o * 136 + f];
        p[0] = (_Float16)v.x; p[1] = (_Float16)v.y;
        p[2] = (_Float16)v.z; p[3] = (_Float16)v.w;
    }
    __syncthreads();

    const int base = blockIdx.x * 64 + wid * 16;
    if (base + 16 > n_nodes) return;   // N % 16 == 0 here

    const int hi = lane >> 4;
    const int nx = lane & 15;

    f16x8 bh[4];
#pragma unroll
    for (int kt = 0; kt < 4; ++kt) {
#pragma unroll
        for (int j = 0; j < 8; ++j)
            bh[kt][j] = (nx < 3) ? (_Float16)head_w[nx * NF + kt * 32 + hi * 8 + j] : (_Float16)0.f;
    }

    const __half* xs[4] = {x0, s1, s2, s3};
    f16x8 a[4][4];
#pragma unroll
    for (int k = 0; k < 4; ++k) {
        const __half* xp = xs[k];
#pragma unroll
        for (int kt = 0; kt < 4; ++kt)
            a[k][kt] = *reinterpret_cast<const f16x8*>(xp + (size_t)(base + nx) * NF + kt * 32 + hi * 8);
    }

    f32x4 accL[4];
#pragma unroll
    for (int k = 0; k < 4; ++k) accL[k] = (f32x4){0.f, 0.f, 0.f, 0.f};
#pragma unroll
    for (int k = 0; k < 4; ++k)
#pragma unroll
        for (int kt = 0; kt < 4; ++kt)
            accL[k] = __builtin_amdgcn_mfma_f32_16x16x32_f16(a[k][kt], bh[kt], accL[k], 0, 0, 0);

    float4 in4 = *reinterpret_cast<const float4*>(&invnv[base + hi * 4]);
    float inr[4] = {in4.x, in4.y, in4.z, in4.w};
    float hb = (nx < 3) ? head_b[nx] : 0.f;
    float al0 = alpha[0], al1 = alpha[1], al2 = alpha[2], al3 = alpha[3];

#pragma unroll
    for (int r = 0; r < 4; ++r) {
        float ivx = inr[r];
        float l0 = accL[0][r] + hb;
        float l1 = fmaf(accL[1][r], ivx, hb);
        float l2 = fmaf(accL[2][r], ivx, hb);
        float l3 = fmaf(accL[3][r], ivx, hb);
        float mx = fmaxf(fmaxf(l0, l1), fmaxf(l2, l3));
        float e0 = __expf(l0 - mx), e1 = __expf(l1 - mx);
        float e2 = __expf(l2 - mx), e3 = __expf(l3 - mx);
        float s = e0 + e1 + e2 + e3;
        float inv = 1.f / s;
        float ls = __logf(s);
        float p0 = e0 * inv, p1 = e1 * inv, p2 = e2 * inv, p3 = e3 * inv;
        bool act = (nx < 3);
        float g0 = act ? p0 : 0.f, g1 = act ? p1 : 0.f;
        float g2 = act ? p2 : 0.f, g3 = act ? p3 : 0.f;
        float et = act ? -(p0 * (l0 - mx - ls) + p1 * (l1 - mx - ls) +
                           p2 * (l2 - mx - ls) + p3 * (l3 - mx - ls)) : 0.f;
        g0 += __shfl_xor(g0, 1, 64); g0 += __shfl_xor(g0, 2, 64);
        g1 += __shfl_xor(g1, 1, 64); g1 += __shfl_xor(g1, 2, 64);
        g2 += __shfl_xor(g2, 1, 64); g2 += __shfl_xor(g2, 2, 64);
        g3 += __shfl_xor(g3, 1, 64); g3 += __shfl_xor(g3, 2, 64);
        et += __shfl_xor(et, 1, 64); et += __shfl_xor(et, 2, 64);
        if (nx == 0) {
            int m = hi * 4 + r;
            wlds[wid][0][m] = al0 * g0;
            wlds[wid][1][m] = al1 * g1 * ivx;
            wlds[wid][2][m] = al2 * g2 * ivx;
            wlds[wid][3][m] = al3 * g3 * ivx;
            out_ent[base + m] = et;
        }
    }

    float ww0 = wlds[wid][0][nx];
    float ww1 = wlds[wid][1][nx];
    float ww2 = wlds[wid][2][nx];
    float ww3 = wlds[wid][3][nx];
    f16x8 ca[4];
#pragma unroll
    for (int kt = 0; kt < 4; ++kt) {
#pragma unroll
        for (int j = 0; j < 8; ++j) {
            float c = ww0 * (float)a[0][kt][j] + ww1 * (float)a[1][kt][j]
                    + ww2 * (float)a[2][kt][j] + ww3 * (float)a[3][kt][j];
            ca[kt][j] = (_Float16)c;
        }
    }

#pragma unroll
    for (int nt = 0; nt < 8; ++nt) {
        f32x4 acc = (f32x4){0.f, 0.f, 0.f, 0.f};
#pragma unroll
        for (int kt = 0; kt < 4; ++kt) {
            f16x8 b = *reinterpret_cast<const f16x8*>(&fcw[(nt * 16 + nx) * 136 + kt * 32 + hi * 8]);
            acc = __builtin_amdgcn_mfma_f32_16x16x32_f16(ca[kt], b, acc, 0, 0, 0);
        }
        float fcb4 = 4.f * fc_b[nt * 16 + nx];
#pragma unroll
        for (int r = 0; r < 4; ++r)
            out_res[(size_t)(base + hi * 4 + r) * NF + nt * 16 + nx] = acc[r] + fcb4;
    }
}

// ---------------- launch ----------------
extern "C" void kernel_launch(void* const* d_in, const int* in_sizes, int n_in,
                              void* d_out, int out_size, void* d_ws, size_t ws_size,
                              hipStream_t stream) {
    const float* feat   = (const float*)d_in[0];
    const float* fc_w   = (const float*)d_in[1];
    const float* fc_b   = (const float*)d_in[2];
    const float* alpha  = (const float*)d_in[3];
    const float* head_w = (const float*)d_in[4];
    const float* head_b = (const float*)d_in[5];
    const int*   src    = (const int*)d_in[6];
    const int*   dst    = (const int*)d_in[7];

    const int N = in_sizes[0] / NF;
    const int E = in_sizes[6];
    const int nb = (N + 127) / 128;       // buckets; N <= 131072

    char* ws = (char*)d_ws;
    size_t pos = 0;
    auto alloc = [&](size_t bytes) -> char* {
        char* p = ws + pos;
        pos = (pos + bytes + 255) & ~(size_t)255;
        return p;
    };
    int*    cnt   = (int*)   alloc((size_t)NCHUNK * NBMAX * 4);
    int*    T     = (int*)   alloc((size_t)NBMAX * 4);
    int*    boff  = (int*)   alloc((size_t)NBMAX * 4);
    int*    buf   = (int*)   alloc((size_t)E * 4);
    int*    csr   = (int*)   alloc((size_t)E * 4);
    int*    off   = (int*)   alloc((size_t)(N + 1) * 4);
    float*  normv = (float*) alloc((size_t)N * 4);
    __half* normh = (__half*)alloc((size_t)N * 2);
    float*  invnv = (float*) alloc((size_t)N * 4);
    __half* x0    = (__half*)alloc((size_t)N * NF * 2);
    __half* s1    = (__half*)alloc((size_t)N * NF * 2);
    __half* s2    = (__half*)alloc((size_t)N * NF * 2);
    __half* s3    = (__half*)alloc((size_t)N * NF * 2);
    if (pos > ws_size) return;

    float* out_res = (float*)d_out;
    float* out_ent = out_res + (size_t)N * NF;

    const int epc = (E + NCHUNK - 1) / NCHUNK;
    const int n8  = N * NF / 8;

    k_histA    <<<NCHUNK + 512, 256, 0, stream>>>(dst, cnt, E, epc, feat, x0, n8);
    k_redT     <<<nb, NCHUNK, 0, stream>>>(cnt, T);
    k_scanT    <<<1, NBMAX, 0, stream>>>(T, boff, nb);
    k_chunkbase<<<nb, NCHUNK, 0, stream>>>(cnt, boff);
    k_scatC    <<<NCHUNK, 256, 0, stream>>>(src, dst, cnt, buf, E, epc);
    k_bucketD  <<<nb, 256, 0, stream>>>(buf, T, boff, csr, off, normv, normh, invnv, N, E, nb);

    const int gb = (N * 64 + 255) / 256;
    k_gather4<true> <<<gb, 256, 0, stream>>>(x0, csr, off, normv, normh, s1, N);
    k_gather4<false><<<gb, 256, 0, stream>>>(s1, csr, off, normv, normh, s2, N);
    k_gather4<false><<<gb, 256, 0, stream>>>(s2, csr, off, normv, normh, s3, N);

    const int eb = (N + 63) / 64;
    k_epi<<<eb, 256, 0, stream>>>(x0, s1, s2, s3, invnv, fc_w, fc_b,
                                  alpha, head_w, head_b, out_res, out_ent, N);
}